// Round 9
// baseline (7936.304 us; speedup 1.0000x reference)
//
#include <hip/hip_runtime.h>
#include <math.h>

#define BB 16
#define TT 1024
#define FF 128
#define RR 2048
#define HALFR 1024
#define NBLK 256
#define NTHR 512

typedef __attribute__((ext_vector_type(2))) unsigned int u32x2;
typedef __attribute__((ext_vector_type(4))) unsigned int u32x4;
typedef __attribute__((ext_vector_type(8))) short bf16x8;
typedef __attribute__((ext_vector_type(4))) float f32x4;

// ---- coherent (IC-level) memory ops: bypass L1/L2, no fences needed ----
__device__ __forceinline__ u32x4 ldg_sc4u(const unsigned* base, unsigned voff) {
    u32x4 r;
    asm volatile("global_load_dwordx4 %0, %1, %2 sc0 sc1"
                 : "=v"(r) : "v"(voff), "s"(base) : "memory");
    return r;
}
__device__ __forceinline__ u32x2 ldg_sc2u(const unsigned* base, unsigned voff) {
    u32x2 r;
    asm volatile("global_load_dwordx2 %0, %1, %2 sc0 sc1"
                 : "=v"(r) : "v"(voff), "s"(base) : "memory");
    return r;
}
__device__ __forceinline__ void stg_sc1u(unsigned* base, unsigned voff, unsigned v) {
    asm volatile("global_store_dword %0, %1, %2 sc0 sc1"
                 :: "v"(voff), "v"(v), "s"(base) : "memory");
}
__device__ __forceinline__ void wait_vm0() {
    asm volatile("s_waitcnt vmcnt(0)" ::: "memory");
}

__device__ __forceinline__ bf16x8 as_bf16x8(u32x4 u) {
    union { u32x4 u4; bf16x8 b8; } c; c.u4 = u; return c.b8;
}

// split fp32 v -> (hh bits, hl bits), each a bf16 pattern; RTN via +0x8000.
__device__ __forceinline__ void split_bf16(float v, unsigned& hh, unsigned& hl) {
    unsigned uh = (__float_as_uint(v) + 0x8000u) & 0xFFFF0000u;
    float rem = v - __uint_as_float(uh);
    unsigned ul = (__float_as_uint(rem) + 0x8000u) & 0xFFFF0000u;
    hh = uh >> 16; hl = ul >> 16;
}
// pack fp32 into one u32: low16 = bf16(hi part), high16 = bf16(residual)
__device__ __forceinline__ unsigned pack_h(float v) {
    unsigned hh, hl; split_bf16(v, hh, hl);
    return (hl << 16) | hh;
}

// ---------------- init: tagged h0 (buf0 tag=0, buf1 tag=1) + rdEpoch=0 ----------------
__global__ void init_state_kernel(unsigned* __restrict__ hA, unsigned* __restrict__ hB,
                                  const float* __restrict__ start,
                                  unsigned* __restrict__ bar) {
    int idx = blockIdx.x * blockDim.x + threadIdx.x;
    if (idx < BB * RR) {
        hA[idx] = pack_h(start[idx & (RR - 1)]) & ~0x00010000u;  // tag 0 (h_0)
        hB[idx] = 0x00010000u;                                   // tag 1 (poison)
    }
    if (idx < 2048) bar[idx] = 0u;
}

// ---------------- persistent MFMA ESN kernel, tag-in-data dataflow ----------------
// R19 = R17 with the sentinel chain deleted: the DATA certifies itself.
//  R17 (5124us, best) chain: h-store -> drain -> epoch publish -> land ->
//  poll detect -> h load RT = ~2.5us/step of serial IC hops. R18 (per-wave
//  epoch polls) regressed 38%: 8x poll traffic + waves re-converge at the
//  reduce barrier anyway.
//  Tag-in-data: each packed h word donates bit16 (LSB of the LO residual,
//  2^-15 relative — noise) to a step-parity tag (s>>1)&1 for h_s. The
//  consumer's LOAD IS THE POLL: retry the chunk load until all 64 words
//  carry the expected tag. Producer->consumer = 1 IC hop. Parity
//  distinguishes h_t from h_{t+-2}; per-word tags handle line tearing;
//  s_sleep backoff after 2 misses caps retry IC traffic (R18 lesson).
//  Epoch words become READ-completion markers only: tid0 publishes
//  rdEpoch=t right after B1 (reads certified by barrier, no drain).
//  Write-safety (storing h_{t+1} over h_{t-1}) = all rdEpoch >= t-1,
//  one step stale, polled by wave 7 concurrently with the epilogue math.
//  Deleted: store-drain, B3, drain-before-publish. Barriers/step: 2.
//  Deadlock-free: at global min step t, h_t was fully stored during
//  everyone's step t-1; write-safety blocks h_{t+2} overwrites while any
//  reader of h_t still polls (it hasn't published rdEpoch=t yet).
//  Compute/dtype/grid = R17 verbatim (verified): 256 blocks x 512 thr,
//  bh-halved batches, 16-col blocks, split-bf16 3-chain MFMA, in-register
//  hold, x double-buffer prefetch.
__global__ __launch_bounds__(NTHR, 2) void esn_mfma(
    const float* __restrict__ inputs,   // [B,T,F]
    const float* __restrict__ Win,      // [R,F]
    const float* __restrict__ Wrec,     // [R,R]
    const float* __restrict__ bias,     // [R]
    unsigned* __restrict__ hA,          // [B,R] packed+tag
    unsigned* __restrict__ hB,          // [B,R] packed+tag
    float* __restrict__ out,            // [B,T,HALFR]
    unsigned* __restrict__ bar,         // rdEpoch words: [half][128]
    const float* __restrict__ start)
{
    __shared__ __align__(16) float sRed[8 * 256];   // 8 KB

    const int tid  = threadIdx.x;
    const int lane = tid & 63;
    const int wave = tid >> 6;          // 0..7 : K-chunk owner (k in [wave*256,+256))
    const int bh   = blockIdx.x & 1;    // batch half: batches bh*8 .. bh*8+7
    const int cb   = blockIdx.x >> 1;   // col-block 0..127
    const int rb   = cb * 16;           // owned cols rb..rb+15
    const int col  = lane & 15;         // MFMA n (W col) AND m (batch row)
    const int kg   = lane >> 4;         // k-group 0..3 within each 32-chunk
    const int ksb  = wave * 256;
    const bool projb = (rb < HALFR);    // uniform per block (16-col blocks)
    const bool mreal = (col < 8);       // A-operand rows 8..15 are zero pads

    // ---- W_rec -> register fragments (once; reused 1024 steps) ----
    bf16x8 Wh[8], Wl[8];
#pragma unroll
    for (int s = 0; s < 8; ++s) {
        const float* wp = Wrec + (size_t)(rb + col) * RR + ksb + s * 32 + kg * 8;
        const float4 w0 = *(const float4*)wp;
        const float4 w1 = *(const float4*)(wp + 4);
        const float wv[8] = {w0.x, w0.y, w0.z, w0.w, w1.x, w1.y, w1.z, w1.w};
        unsigned hh[8], hl[8];
#pragma unroll
        for (int e = 0; e < 8; ++e) split_bf16(wv[e], hh[e], hl[e]);
        u32x4 ph = { hh[0] | (hh[1] << 16), hh[2] | (hh[3] << 16),
                     hh[4] | (hh[5] << 16), hh[6] | (hh[7] << 16) };
        u32x4 pl = { hl[0] | (hl[1] << 16), hl[2] | (hl[3] << 16),
                     hl[4] | (hl[5] << 16), hl[6] | (hl[7] << 16) };
        Wh[s] = as_bf16x8(ph);
        Wl[s] = as_bf16x8(pl);
    }

    // ---- Win -> register fragments (waves 0-3 of proj blocks; K=128) ----
    bf16x8 Ih = {0,0,0,0,0,0,0,0}, Il = {0,0,0,0,0,0,0,0};
    const bool xwave = projb && (wave < 4);
    if (xwave) {
        const float* ip = Win + (size_t)(rb + col) * FF + wave * 32 + kg * 8;
        const float4 w0 = *(const float4*)ip;
        const float4 w1 = *(const float4*)(ip + 4);
        const float wv[8] = {w0.x, w0.y, w0.z, w0.w, w1.x, w1.y, w1.z, w1.w};
        unsigned hh[8], hl[8];
#pragma unroll
        for (int e = 0; e < 8; ++e) split_bf16(wv[e], hh[e], hl[e]);
        u32x4 ph = { hh[0] | (hh[1] << 16), hh[2] | (hh[3] << 16),
                     hh[4] | (hh[5] << 16), hh[6] | (hh[7] << 16) };
        u32x4 pl = { hl[0] | (hl[1] << 16), hl[2] | (hl[3] << 16),
                     hl[4] | (hl[5] << 16), hl[6] | (hl[7] << 16) };
        Ih = as_bf16x8(ph);
        Il = as_bf16x8(pl);
    }

    // ---- h-load byte offsets (lanes with col<8): batch bh*8+col ----
    const int batm = bh * 8 + (col & 7);
    unsigned voffH[8][2];
#pragma unroll
    for (int s = 0; s < 8; ++s) {
        const unsigned base = (unsigned)(((batm * RR) + ksb + s * 32 + kg * 8) * 4);
        voffH[s][0] = base;
        voffH[s][1] = base + 16;
    }
    // per-lane x base (proj waves, col<8): batch=batm, f = wave*32 + kg*8
    const size_t xbase = (size_t)batm * TT * FF + wave * 32 + kg * 8;

    // ---- epilogue mapping: tid<256 -> (m=tid>>4, n=tid&15); rows m<8 own ----
    const int mE = tid >> 4;
    const int nE = tid & 15;
    const int eBatch = bh * 8 + (mE & 7);
    const int eCol   = rb + nE;
    const bool ownS  = (tid < 256) && (mE < 8);
    const float myBias = bias[eCol];
    const unsigned eOff = (unsigned)((eBatch * RR + eCol) * 4);
    float holdv = start[eCol];          // in-register h_old

    // ---- rdEpoch state (write-safety only) ----
    const unsigned pollAll = (unsigned)((bh * 128 + lane * 2) * 4);  // wave-7 poll
    const unsigned epOff   = (unsigned)((bh * 128 + cb) * 4);        // our word

    // x_t for the first step
    float4 xc0 = {0,0,0,0}, xc1 = {0,0,0,0};
    if (xwave && mreal) {
        const float* xp = inputs + xbase;
        xc0 = *(const float4*)xp;
        xc1 = *(const float4*)(xp + 4);
    }

    for (int t = 0; t < TT; ++t) {
        const unsigned texpm = (((unsigned)t >> 1) & 1u) << 16;  // expected tag of h_t
        const unsigned* hc = (t & 1) ? hB : hA;
        unsigned*       hn = (t & 1) ? hA : hB;

        // 1) x_{t+1} prefetch first (lands under the poll; poll's vm0 covers it).
        float4 xn0 = {0,0,0,0}, xn1 = {0,0,0,0};
        if (xwave && mreal) {
            const int tp1 = (t + 1 < TT) ? (t + 1) : (TT - 1);
            const float* xp = inputs + xbase + (size_t)tp1 * FF;
            xn0 = *(const float4*)xp;
            xn1 = *(const float4*)(xp + 4);
        }

        // 2) Tag-poll: the h load IS the poll. Retry until all 64 words of
        //    my chunk carry tag(h_t). Backoff after 2 misses (IC protection).
        u32x4 hld[16];
        if (!mreal) {
#pragma unroll
            for (int i = 0; i < 16; ++i) hld[i] = (u32x4){0u, 0u, 0u, 0u};
        }
        {
            int miss = 0;
            for (;;) {
                if (mreal) {
#pragma unroll
                    for (int s = 0; s < 8; ++s) {
                        hld[2 * s]     = ldg_sc4u(hc, voffH[s][0]);
                        hld[2 * s + 1] = ldg_sc4u(hc, voffH[s][1]);
                    }
                }
                wait_vm0();
                bool ok = true;
                if (mreal) {
                    u32x4 mm = {0u, 0u, 0u, 0u};
#pragma unroll
                    for (int i = 0; i < 16; ++i) {
                        const u32x4 v = hld[i];
                        mm.x |= v.x ^ texpm;
                        mm.y |= v.y ^ texpm;
                        mm.z |= v.z ^ texpm;
                        mm.w |= v.w ^ texpm;
                    }
                    ok = (((mm.x | mm.y | mm.z | mm.w) & 0x00010000u) == 0u);
                }
                if (__all((int)ok)) break;
                if (++miss > 1) __builtin_amdgcn_s_sleep(8);
            }
        }
        __builtin_amdgcn_sched_barrier(0);      // rule #18: pin MFMA after drain

        // 3) MFMA: 3 chains (Wh*hh + Wh*hl + Wl*hh), K=2048 (+128 proj).
        f32x4 accA = {0.f, 0.f, 0.f, 0.f};
        f32x4 accB = {0.f, 0.f, 0.f, 0.f};
        f32x4 accC = {0.f, 0.f, 0.f, 0.f};
#pragma unroll
        for (int s = 0; s < 8; ++s) {
            const u32x4 pa = hld[2 * s];
            const u32x4 pb = hld[2 * s + 1];
            u32x4 ahh = { (pa.x & 0xFFFFu) | (pa.y << 16),
                          (pa.z & 0xFFFFu) | (pa.w << 16),
                          (pb.x & 0xFFFFu) | (pb.y << 16),
                          (pb.z & 0xFFFFu) | (pb.w << 16) };
            u32x4 ahl = { (pa.x >> 16) | (pa.y & 0xFFFF0000u),
                          (pa.z >> 16) | (pa.w & 0xFFFF0000u),
                          (pb.x >> 16) | (pb.y & 0xFFFF0000u),
                          (pb.z >> 16) | (pb.w & 0xFFFF0000u) };
            const bf16x8 Ah = as_bf16x8(ahh);
            const bf16x8 Al = as_bf16x8(ahl);
            accA = __builtin_amdgcn_mfma_f32_16x16x32_bf16(Ah, Wh[s], accA, 0, 0, 0);
            accB = __builtin_amdgcn_mfma_f32_16x16x32_bf16(Al, Wh[s], accB, 0, 0, 0);
            accC = __builtin_amdgcn_mfma_f32_16x16x32_bf16(Ah, Wl[s], accC, 0, 0, 0);
        }
        if (xwave) {
            const float xv[8] = {xc0.x, xc0.y, xc0.z, xc0.w, xc1.x, xc1.y, xc1.z, xc1.w};
            unsigned hh[8], hl[8];
#pragma unroll
            for (int e = 0; e < 8; ++e) split_bf16(xv[e], hh[e], hl[e]);
            u32x4 ph = { hh[0] | (hh[1] << 16), hh[2] | (hh[3] << 16),
                         hh[4] | (hh[5] << 16), hh[6] | (hh[7] << 16) };
            u32x4 pl = { hl[0] | (hl[1] << 16), hl[2] | (hl[3] << 16),
                         hl[4] | (hl[5] << 16), hl[6] | (hl[7] << 16) };
            const bf16x8 Axh = as_bf16x8(ph);
            const bf16x8 Axl = as_bf16x8(pl);
            accA = __builtin_amdgcn_mfma_f32_16x16x32_bf16(Axh, Ih, accA, 0, 0, 0);
            accB = __builtin_amdgcn_mfma_f32_16x16x32_bf16(Axl, Ih, accB, 0, 0, 0);
            accC = __builtin_amdgcn_mfma_f32_16x16x32_bf16(Axh, Il, accC, 0, 0, 0);
        }
        const f32x4 acc = accA + accB + accC;

        // 4) Cross-wave reduce staging.
        *(f32x4*)&sRed[wave * 256 + lane * 4] = acc;
        __syncthreads();                                    // B1: sRed ready + reads done

        // 5) Publish rdEpoch=t (reads of h_t certified by B1; plain store,
        //    no drain). Epilogue math runs concurrently with wave-7's
        //    lagged write-safety poll (all rdEpoch >= t-1: everyone done
        //    READING h_{t-1}, whose buffer our h_{t+1} stores overwrite).
        if (tid == 0) stg_sc1u(bar, epOff, (unsigned)t);
        float vnew = 0.0f;
        if (tid < 256) {
            const int ridx = ((mE >> 2) * 16 + nE) * 4 + (mE & 3);
            float val = 0.f;
#pragma unroll
            for (int w = 0; w < 8; ++w) val += sRed[w * 256 + ridx];
            if (ownS) {
                const float pre = val + myBias;
                vnew = 0.05f * holdv + 0.95f * tanhf(pre);
                holdv = vnew;
            }
        }
        if (wave == 7 && t > 0) {
            const unsigned need = (unsigned)(t - 1);
            for (;;) {
                const u32x2 v = ldg_sc2u(bar, pollAll);
                wait_vm0();
                if (__all((int)((v.x >= need) && (v.y >= need)))) break;
            }
        }
        __syncthreads();                                    // B2: safe to store

        // 6) Tagged stores (h full 64B lines; out). No drain, no publish hop:
        //    consumers detect the tags directly; own-block races self-heal
        //    via the tag retry.
        if (ownS) {
            unsigned w = pack_h(vnew);
            w = (w & 0xFFFEFFFFu) | ((((unsigned)(t + 1) >> 1) & 1u) << 16);
            stg_sc1u(hn, eOff, w);
            if (eCol >= HALFR)
                out[((size_t)eBatch * TT + t) * HALFR + (eCol - HALFR)] = vnew;
        }

        // rotate x double-buffer
        xc0 = xn0; xc1 = xn1;
    }
}

// ---------------- fallback path (proven R1): fp32, 1024 launches ----------------

__global__ void init_h_kernel(float* __restrict__ h, const float* __restrict__ start) {
    int idx = blockIdx.x * blockDim.x + threadIdx.x;
    if (idx < BB * RR) h[idx] = start[idx & (RR - 1)];
}

__global__ __launch_bounds__(512, 2) void step_kernel(
    const float* __restrict__ inputs, const float* __restrict__ Win,
    const float* __restrict__ Wrec, const float* __restrict__ bias,
    const float* __restrict__ h_cur, float* __restrict__ h_next,
    float* __restrict__ out, int t)
{
    const int tid  = threadIdx.x;
    const int wave = tid >> 6;
    const int half = (tid >> 5) & 1;
    const int kl   = tid & 31;
    const int b    = wave * 2 + half;
    const int r0   = blockIdx.x * 8;

    float acc[8];
#pragma unroll
    for (int r = 0; r < 8; ++r) acc[r] = 0.0f;

    if (r0 < HALFR) {
        const float4 in4 = *reinterpret_cast<const float4*>(
            inputs + ((size_t)b * TT + t) * FF + kl * 4);
#pragma unroll
        for (int r = 0; r < 8; ++r) {
            const float4 w4 = *reinterpret_cast<const float4*>(
                Win + (size_t)(r0 + r) * FF + kl * 4);
            acc[r] += in4.x * w4.x + in4.y * w4.y + in4.z * w4.z + in4.w * w4.w;
        }
    }

    const float* hb = h_cur + (size_t)b * RR;
#pragma unroll 2
    for (int j = 0; j < 16; ++j) {
        const int k = kl * 4 + j * 128;
        const float4 h4 = *reinterpret_cast<const float4*>(hb + k);
#pragma unroll
        for (int r = 0; r < 8; ++r) {
            const float4 w4 = *reinterpret_cast<const float4*>(
                Wrec + (size_t)(r0 + r) * RR + k);
            acc[r] = fmaf(h4.x, w4.x, acc[r]);
            acc[r] = fmaf(h4.y, w4.y, acc[r]);
            acc[r] = fmaf(h4.z, w4.z, acc[r]);
            acc[r] = fmaf(h4.w, w4.w, acc[r]);
        }
    }

#pragma unroll
    for (int r = 0; r < 8; ++r) {
        float v = acc[r];
        v += __shfl_xor(v, 1);  v += __shfl_xor(v, 2);
        v += __shfl_xor(v, 4);  v += __shfl_xor(v, 8);
        v += __shfl_xor(v, 16);
        acc[r] = v;
    }

    __shared__ float red[BB][8];
    if (kl == 0) {
#pragma unroll
        for (int r = 0; r < 8; ++r) red[b][r] = acc[r];
    }
    __syncthreads();

    if (tid < BB * 8) {
        const int rr = tid & 7, bb = tid >> 3;
        const int r  = r0 + rr;
        const float pre = red[bb][rr] + bias[r];
        const float h_old = h_cur[(size_t)bb * RR + r];
        const float hn = 0.05f * h_old + 0.95f * tanhf(pre);
        h_next[(size_t)bb * RR + r] = hn;
        if (r0 >= HALFR) out[((size_t)bb * TT + t) * HALFR + (r - HALFR)] = hn;
    }
}

// ---------------- launch ----------------

extern "C" void kernel_launch(void* const* d_in, const int* in_sizes, int n_in,
                              void* d_out, int out_size, void* d_ws, size_t ws_size,
                              hipStream_t stream) {
    const float* inputs = (const float*)d_in[0];   // [B,T,F]
    const float* Win    = (const float*)d_in[1];   // [R,F]
    const float* Wrec   = (const float*)d_in[2];   // [R,R]
    const float* bias   = (const float*)d_in[3];   // [R]
    const float* start  = (const float*)d_in[4];   // [R]
    float* out = (float*)d_out;                    // [B,T,HALFR]

    unsigned* hA = (unsigned*)d_ws;                // [B,R] packed+tag
    unsigned* hB = hA + (size_t)BB * RR;           // [B,R] packed+tag
    unsigned* bar = hB + (size_t)BB * RR;          // rdEpoch words
    const size_t need = (size_t)BB * RR * 4 * 2 + 8192;

    if (ws_size >= need) {
        init_state_kernel<<<64, 512, 0, stream>>>(hA, hB, start, bar);
        void* args[] = { (void*)&inputs, (void*)&Win, (void*)&Wrec, (void*)&bias,
                         (void*)&hA, (void*)&hB, (void*)&out, (void*)&bar,
                         (void*)&start };
        hipLaunchCooperativeKernel((void*)esn_mfma, dim3(NBLK), dim3(NTHR),
                                   args, 0, stream);
    } else {
        float* fA = (float*)d_ws;
        float* fB = fA + (size_t)BB * RR;
        init_h_kernel<<<(BB * RR + 255) / 256, 256, 0, stream>>>(fA, start);
        for (int t = 0; t < TT; ++t) {
            const float* hcur = (t & 1) ? fB : fA;
            float*       hnxt = (t & 1) ? fA : fB;
            step_kernel<<<256, 512, 0, stream>>>(inputs, Win, Wrec, bias, hcur, hnxt, out, t);
        }
    }
}

// Round 10
// 4955.227 us; speedup vs baseline: 1.6016x; 1.6016x over previous
//
#include <hip/hip_runtime.h>
#include <math.h>

#define BB 16
#define TT 1024
#define FF 128
#define RR 2048
#define HALFR 1024
#define NBLK 256
#define NTHR 512

typedef __attribute__((ext_vector_type(4))) unsigned int u32x4;
typedef __attribute__((ext_vector_type(8))) short bf16x8;
typedef __attribute__((ext_vector_type(4))) float f32x4;

// ---- coherent (IC-level) memory ops: bypass L1/L2, no fences needed ----
__device__ __forceinline__ u32x4 ldg_sc4u(const unsigned* base, unsigned voff) {
    u32x4 r;
    asm volatile("global_load_dwordx4 %0, %1, %2 sc0 sc1"
                 : "=v"(r) : "v"(voff), "s"(base) : "memory");
    return r;
}
__device__ __forceinline__ unsigned ldg_sc1r(const unsigned* base, unsigned voff) {
    unsigned r;
    asm volatile("global_load_dword %0, %1, %2 sc0 sc1"
                 : "=v"(r) : "v"(voff), "s"(base) : "memory");
    return r;
}
__device__ __forceinline__ void stg_sc1u(unsigned* base, unsigned voff, unsigned v) {
    asm volatile("global_store_dword %0, %1, %2 sc0 sc1"
                 :: "v"(voff), "v"(v), "s"(base) : "memory");
}
__device__ __forceinline__ void wait_vm0() {
    asm volatile("s_waitcnt vmcnt(0)" ::: "memory");
}

__device__ __forceinline__ bf16x8 as_bf16x8(u32x4 u) {
    union { u32x4 u4; bf16x8 b8; } c; c.u4 = u; return c.b8;
}

// split fp32 v -> (hh bits, hl bits), each a bf16 pattern; RTN via +0x8000.
__device__ __forceinline__ void split_bf16(float v, unsigned& hh, unsigned& hl) {
    unsigned uh = (__float_as_uint(v) + 0x8000u) & 0xFFFF0000u;
    float rem = v - __uint_as_float(uh);
    unsigned ul = (__float_as_uint(rem) + 0x8000u) & 0xFFFF0000u;
    hh = uh >> 16; hl = ul >> 16;
}
// pack fp32 into one u32: low16 = bf16(hi part), high16 = bf16(residual)
__device__ __forceinline__ unsigned pack_h(float v) {
    unsigned hh, hl; split_bf16(v, hh, hl);
    return (hl << 16) | hh;
}

// ---------------- init: packed h0 + epoch words ----------------
__global__ void init_state_kernel(unsigned* __restrict__ h, const float* __restrict__ start,
                                  unsigned* __restrict__ bar) {
    int idx = blockIdx.x * blockDim.x + threadIdx.x;
    if (idx < BB * RR) h[idx] = pack_h(start[idx & (RR - 1)]);
    if (idx < 2048) bar[idx] = 0u;
}

// ---------------- persistent MFMA ESN kernel, quarter-split dataflow ----------------
// R20 = R17's proven epoch protocol on a SMALLER lockstep domain.
//  R17 (5124us, best): 2 halves x 128 col-blocks of 16 cols; every h word
//  read by 128 blocks -> 16MB/step IC broadcast, straggler max over 128,
//  128-word poll. R18 (per-wave poll) and R19 (tag-in-data) both regressed
//  on poll traffic -> keep R17's single tiny wave-0 poll; shrink the DOMAIN.
//  Grid = 4 independent QUARTERS (4 batches each) x 64 col-blocks of 32
//  cols: cliques 128->64 blocks, poll 128->64 words (1 dword/lane),
//  broadcast 16->8 MB/step, h stores 128B runs. Quarters never interact.
//  Register fit for 32-col W (128 VGPR): the per-lane hld[16] (64 VGPR) is
//  replaced by a cooperative WAVE-PRIVATE LDS h-stage: 64 lanes load the
//  wave's 4KB chunk coalesced (64B/lane, 4 dwordx4 = 16 VGPR in flight),
//  ds_write, each lane ds_reads its fragment (16 b128/lane/step, hidden
//  under MFMA; wave-private -> no block barrier). Cross-chains merged:
//  accX accumulates Al*Wh + Ah*Wl (same products, fp32 accum).
//  A-operand rows 4..15 are batch-duplicates ((col&3) clamp) — finite,
//  ignored by the epilogue (rows 0..3 only).
//  Protocol verbatim R17: loop-top wave-0 poll (all 64 epochs >= t gives
//  data-ready AND double-buffer write-safety by the same induction),
//  syncthreads, single-drain loads, B1 reduce, epilogue+stores, drain,
//  B3, tid0 publishes epoch t+1.
__global__ __launch_bounds__(NTHR, 2) void esn_mfma(
    const float* __restrict__ inputs,   // [B,T,F]
    const float* __restrict__ Win,      // [R,F]
    const float* __restrict__ Wrec,     // [R,R]
    const float* __restrict__ bias,     // [R]
    unsigned* __restrict__ hA,          // [B,R] packed
    unsigned* __restrict__ hB,          // [B,R] packed
    float* __restrict__ out,            // [B,T,HALFR]
    unsigned* __restrict__ bar,         // epoch words: [quarter][64]
    const float* __restrict__ start)
{
    __shared__ __align__(16) unsigned sH[8 * 1024];   // 32 KB: 8 waves x 4KB h-stage
    __shared__ __align__(16) float sRed[16 * 256];    // 16 KB: 8 waves x 2 tiles

    const int tid  = threadIdx.x;
    const int lane = tid & 63;
    const int wave = tid >> 6;          // 0..7 : K-chunk owner (k in [wave*256,+256))
    const int q    = blockIdx.x & 3;    // quarter: batches q*4 .. q*4+3
    const int cb   = blockIdx.x >> 2;   // col-block 0..63
    const int rb   = cb * 32;           // owned cols rb..rb+31
    const int col  = lane & 15;         // MFMA n within tile / m (batch row)
    const int kg   = lane >> 4;         // k-group 0..3 within each 32-chunk
    const int ksb  = wave * 256;
    const bool projb = (rb < HALFR);    // uniform per block (cb < 32)
    const bool xwave = projb && (wave < 4);

    // ---- W_rec -> register fragments: 2 n-tiles x 8 k-steps (once) ----
    bf16x8 Wh[2][8], Wl[2][8];
#pragma unroll
    for (int nt = 0; nt < 2; ++nt)
#pragma unroll
        for (int s = 0; s < 8; ++s) {
            const float* wp = Wrec + (size_t)(rb + nt * 16 + col) * RR + ksb + s * 32 + kg * 8;
            const float4 w0 = *(const float4*)wp;
            const float4 w1 = *(const float4*)(wp + 4);
            const float wv[8] = {w0.x, w0.y, w0.z, w0.w, w1.x, w1.y, w1.z, w1.w};
            unsigned hh[8], hl[8];
#pragma unroll
            for (int e = 0; e < 8; ++e) split_bf16(wv[e], hh[e], hl[e]);
            u32x4 ph = { hh[0] | (hh[1] << 16), hh[2] | (hh[3] << 16),
                         hh[4] | (hh[5] << 16), hh[6] | (hh[7] << 16) };
            u32x4 pl = { hl[0] | (hl[1] << 16), hl[2] | (hl[3] << 16),
                         hl[4] | (hl[5] << 16), hl[6] | (hl[7] << 16) };
            Wh[nt][s] = as_bf16x8(ph);
            Wl[nt][s] = as_bf16x8(pl);
        }

    // ---- Win -> register fragments (waves 0-3 of proj blocks; K=128) ----
    bf16x8 Ih[2] = { {0,0,0,0,0,0,0,0}, {0,0,0,0,0,0,0,0} };
    bf16x8 Il[2] = { {0,0,0,0,0,0,0,0}, {0,0,0,0,0,0,0,0} };
    if (xwave) {
#pragma unroll
        for (int nt = 0; nt < 2; ++nt) {
            const float* ip = Win + (size_t)(rb + nt * 16 + col) * FF + wave * 32 + kg * 8;
            const float4 w0 = *(const float4*)ip;
            const float4 w1 = *(const float4*)(ip + 4);
            const float wv[8] = {w0.x, w0.y, w0.z, w0.w, w1.x, w1.y, w1.z, w1.w};
            unsigned hh[8], hl[8];
#pragma unroll
            for (int e = 0; e < 8; ++e) split_bf16(wv[e], hh[e], hl[e]);
            u32x4 ph = { hh[0] | (hh[1] << 16), hh[2] | (hh[3] << 16),
                         hh[4] | (hh[5] << 16), hh[6] | (hh[7] << 16) };
            u32x4 pl = { hl[0] | (hl[1] << 16), hl[2] | (hl[3] << 16),
                         hl[4] | (hl[5] << 16), hl[6] | (hl[7] << 16) };
            Ih[nt] = as_bf16x8(ph);
            Il[nt] = as_bf16x8(pl);
        }
    }

    // ---- cooperative h-load addressing: lane covers 64B of the wave's
    //      4KB chunk (batch q*4 + lane>>4, words (lane&15)*16 .. +15) ----
    const unsigned gbase = (unsigned)((((q * 4 + (lane >> 4)) * RR)
                                       + ksb + (lane & 15) * 16) * 4);
    const int swb = wave * 1024 + lane * 16;               // LDS write base (words)
    const int srb = wave * 1024 + (col & 3) * 256 + kg * 8; // LDS read base (+ s*32, +4)

    // ---- x addressing (proj waves): batch q*4+(col&3), f = wave*32+kg*8 ----
    const size_t xrow = (size_t)(q * 4 + (col & 3)) * TT * FF + wave * 32 + kg * 8;

    // ---- epilogue mapping: tid<128 -> (m=tid>>5, n=tid&31) ----
    const int mE = tid >> 5;
    const int nE = tid & 31;
    const int eBatch = q * 4 + (mE & 3);
    const int eCol   = rb + nE;
    const float myBias = bias[eCol];
    const unsigned eOff = (unsigned)((eBatch * RR + eCol) * 4);
    float holdv = start[eCol];          // in-register h_old (R16-proven)
    const int ntE  = nE >> 4;
    const int ridx = (nE & 15) * 4 + (mE & 3);

    // ---- epoch state: 64 words per quarter ----
    const unsigned pollOff = (unsigned)((q * 64 + lane) * 4);
    const unsigned epOff   = (unsigned)((q * 64 + cb) * 4);

    for (int t = 0; t < TT; ++t) {
        const unsigned tgt = (unsigned)t;
        const unsigned* hc = (t & 1) ? hB : hA;
        unsigned*       hn = (t & 1) ? hA : hB;

        // 1) Wave-0 poll: all 64 epochs of my quarter >= t (data-ready AND
        //    write-safety, R17 induction). One dword per lane.
        if (wave == 0) {
            for (;;) {
                const unsigned v = ldg_sc1r(bar, pollOff);
                wait_vm0();
                if (__all((int)(v >= tgt))) break;
            }
        }
        __syncthreads();

        // 2) Cooperative h chunk load (coalesced 64B/lane) + x load; one drain.
        u32x4 g0 = ldg_sc4u(hc, gbase);
        u32x4 g1 = ldg_sc4u(hc, gbase + 16u);
        u32x4 g2 = ldg_sc4u(hc, gbase + 32u);
        u32x4 g3 = ldg_sc4u(hc, gbase + 48u);
        float4 xc0 = {0,0,0,0}, xc1 = {0,0,0,0};
        if (xwave) {
            const float* xp = inputs + xrow + (size_t)t * FF;
            xc0 = *(const float4*)xp;
            xc1 = *(const float4*)(xp + 4);
        }
        wait_vm0();
        __builtin_amdgcn_sched_barrier(0);      // rule #18

        // 3) Wave-private LDS stage (no block barrier; lgkmcnt by compiler).
        *(u32x4*)&sH[swb]      = g0;
        *(u32x4*)&sH[swb + 4]  = g1;
        *(u32x4*)&sH[swb + 8]  = g2;
        *(u32x4*)&sH[swb + 12] = g3;

        // 4) MFMA: per s read my fragment from LDS, 2 n-tiles x
        //    {Ah*Wh -> accA, Al*Wh + Ah*Wl -> accX}.
        f32x4 accA[2] = { {0.f,0.f,0.f,0.f}, {0.f,0.f,0.f,0.f} };
        f32x4 accX[2] = { {0.f,0.f,0.f,0.f}, {0.f,0.f,0.f,0.f} };
#pragma unroll
        for (int s = 0; s < 8; ++s) {
            const u32x4 pa = *(const u32x4*)&sH[srb + s * 32];
            const u32x4 pb = *(const u32x4*)&sH[srb + s * 32 + 4];
            u32x4 ahh = { (pa.x & 0xFFFFu) | (pa.y << 16),
                          (pa.z & 0xFFFFu) | (pa.w << 16),
                          (pb.x & 0xFFFFu) | (pb.y << 16),
                          (pb.z & 0xFFFFu) | (pb.w << 16) };
            u32x4 ahl = { (pa.x >> 16) | (pa.y & 0xFFFF0000u),
                          (pa.z >> 16) | (pa.w & 0xFFFF0000u),
                          (pb.x >> 16) | (pb.y & 0xFFFF0000u),
                          (pb.z >> 16) | (pb.w & 0xFFFF0000u) };
            const bf16x8 Ah = as_bf16x8(ahh);
            const bf16x8 Al = as_bf16x8(ahl);
#pragma unroll
            for (int nt = 0; nt < 2; ++nt) {
                accA[nt] = __builtin_amdgcn_mfma_f32_16x16x32_bf16(Ah, Wh[nt][s], accA[nt], 0, 0, 0);
                accX[nt] = __builtin_amdgcn_mfma_f32_16x16x32_bf16(Al, Wh[nt][s], accX[nt], 0, 0, 0);
                accX[nt] = __builtin_amdgcn_mfma_f32_16x16x32_bf16(Ah, Wl[nt][s], accX[nt], 0, 0, 0);
            }
        }
        if (xwave) {
            const float xv[8] = {xc0.x, xc0.y, xc0.z, xc0.w, xc1.x, xc1.y, xc1.z, xc1.w};
            unsigned hh[8], hl[8];
#pragma unroll
            for (int e = 0; e < 8; ++e) split_bf16(xv[e], hh[e], hl[e]);
            u32x4 ph = { hh[0] | (hh[1] << 16), hh[2] | (hh[3] << 16),
                         hh[4] | (hh[5] << 16), hh[6] | (hh[7] << 16) };
            u32x4 pl = { hl[0] | (hl[1] << 16), hl[2] | (hl[3] << 16),
                         hl[4] | (hl[5] << 16), hl[6] | (hl[7] << 16) };
            const bf16x8 Axh = as_bf16x8(ph);
            const bf16x8 Axl = as_bf16x8(pl);
#pragma unroll
            for (int nt = 0; nt < 2; ++nt) {
                accA[nt] = __builtin_amdgcn_mfma_f32_16x16x32_bf16(Axh, Ih[nt], accA[nt], 0, 0, 0);
                accX[nt] = __builtin_amdgcn_mfma_f32_16x16x32_bf16(Axl, Ih[nt], accX[nt], 0, 0, 0);
                accX[nt] = __builtin_amdgcn_mfma_f32_16x16x32_bf16(Axh, Il[nt], accX[nt], 0, 0, 0);
            }
        }

        // 5) Cross-wave reduce staging: 16 partial tiles.
        *(f32x4*)&sRed[(wave * 2 + 0) * 256 + lane * 4] = accA[0] + accX[0];
        *(f32x4*)&sRed[(wave * 2 + 1) * 256 + lane * 4] = accA[1] + accX[1];
        __syncthreads();                                    // B1: sRed ready + reads done

        // 6) Epilogue (tid<128): sum 8 waves, tanh, store h (128B runs) + out.
        if (tid < 128) {
            float val = 0.f;
#pragma unroll
            for (int w = 0; w < 8; ++w) val += sRed[(w * 2 + ntE) * 256 + ridx];
            const float pre  = val + myBias;
            const float vnew = 0.05f * holdv + 0.95f * tanhf(pre);
            holdv = vnew;
            stg_sc1u(hn, eOff, pack_h(vnew));
            if (eCol >= HALFR)
                out[((size_t)eBatch * TT + t) * HALFR + (eCol - HALFR)] = vnew;
        }

        // 7) Drain own stores, block-sync, publish epoch t+1.
        wait_vm0();
        __syncthreads();                                    // B3: all drained
        if (tid == 0) stg_sc1u(bar, epOff, (unsigned)(t + 1));
    }
}

// ---------------- fallback path (proven R1): fp32, 1024 launches ----------------

__global__ void init_h_kernel(float* __restrict__ h, const float* __restrict__ start) {
    int idx = blockIdx.x * blockDim.x + threadIdx.x;
    if (idx < BB * RR) h[idx] = start[idx & (RR - 1)];
}

__global__ __launch_bounds__(512, 2) void step_kernel(
    const float* __restrict__ inputs, const float* __restrict__ Win,
    const float* __restrict__ Wrec, const float* __restrict__ bias,
    const float* __restrict__ h_cur, float* __restrict__ h_next,
    float* __restrict__ out, int t)
{
    const int tid  = threadIdx.x;
    const int wave = tid >> 6;
    const int half = (tid >> 5) & 1;
    const int kl   = tid & 31;
    const int b    = wave * 2 + half;
    const int r0   = blockIdx.x * 8;

    float acc[8];
#pragma unroll
    for (int r = 0; r < 8; ++r) acc[r] = 0.0f;

    if (r0 < HALFR) {
        const float4 in4 = *reinterpret_cast<const float4*>(
            inputs + ((size_t)b * TT + t) * FF + kl * 4);
#pragma unroll
        for (int r = 0; r < 8; ++r) {
            const float4 w4 = *reinterpret_cast<const float4*>(
                Win + (size_t)(r0 + r) * FF + kl * 4);
            acc[r] += in4.x * w4.x + in4.y * w4.y + in4.z * w4.z + in4.w * w4.w;
        }
    }

    const float* hb = h_cur + (size_t)b * RR;
#pragma unroll 2
    for (int j = 0; j < 16; ++j) {
        const int k = kl * 4 + j * 128;
        const float4 h4 = *reinterpret_cast<const float4*>(hb + k);
#pragma unroll
        for (int r = 0; r < 8; ++r) {
            const float4 w4 = *reinterpret_cast<const float4*>(
                Wrec + (size_t)(r0 + r) * RR + k);
            acc[r] = fmaf(h4.x, w4.x, acc[r]);
            acc[r] = fmaf(h4.y, w4.y, acc[r]);
            acc[r] = fmaf(h4.z, w4.z, acc[r]);
            acc[r] = fmaf(h4.w, w4.w, acc[r]);
        }
    }

#pragma unroll
    for (int r = 0; r < 8; ++r) {
        float v = acc[r];
        v += __shfl_xor(v, 1);  v += __shfl_xor(v, 2);
        v += __shfl_xor(v, 4);  v += __shfl_xor(v, 8);
        v += __shfl_xor(v, 16);
        acc[r] = v;
    }

    __shared__ float red[BB][8];
    if (kl == 0) {
#pragma unroll
        for (int r = 0; r < 8; ++r) red[b][r] = acc[r];
    }
    __syncthreads();

    if (tid < BB * 8) {
        const int rr = tid & 7, bb = tid >> 3;
        const int r  = r0 + rr;
        const float pre = red[bb][rr] + bias[r];
        const float h_old = h_cur[(size_t)bb * RR + r];
        const float hn = 0.05f * h_old + 0.95f * tanhf(pre);
        h_next[(size_t)bb * RR + r] = hn;
        if (r0 >= HALFR) out[((size_t)bb * TT + t) * HALFR + (r - HALFR)] = hn;
    }
}

// ---------------- launch ----------------

extern "C" void kernel_launch(void* const* d_in, const int* in_sizes, int n_in,
                              void* d_out, int out_size, void* d_ws, size_t ws_size,
                              hipStream_t stream) {
    const float* inputs = (const float*)d_in[0];   // [B,T,F]
    const float* Win    = (const float*)d_in[1];   // [R,F]
    const float* Wrec   = (const float*)d_in[2];   // [R,R]
    const float* bias   = (const float*)d_in[3];   // [R]
    const float* start  = (const float*)d_in[4];   // [R]
    float* out = (float*)d_out;                    // [B,T,HALFR]

    unsigned* hA = (unsigned*)d_ws;                // [B,R] packed bf16-pair
    unsigned* hB = hA + (size_t)BB * RR;           // [B,R] packed
    unsigned* bar = hB + (size_t)BB * RR;          // epoch words
    const size_t need = (size_t)BB * RR * 4 * 2 + 8192;

    if (ws_size >= need) {
        init_state_kernel<<<64, 512, 0, stream>>>(hA, start, bar);
        void* args[] = { (void*)&inputs, (void*)&Win, (void*)&Wrec, (void*)&bias,
                         (void*)&hA, (void*)&hB, (void*)&out, (void*)&bar,
                         (void*)&start };
        hipLaunchCooperativeKernel((void*)esn_mfma, dim3(NBLK), dim3(NTHR),
                                   args, 0, stream);
    } else {
        float* fA = (float*)d_ws;
        float* fB = fA + (size_t)BB * RR;
        init_h_kernel<<<(BB * RR + 255) / 256, 256, 0, stream>>>(fA, start);
        for (int t = 0; t < TT; ++t) {
            const float* hcur = (t & 1) ? fB : fA;
            float*       hnxt = (t & 1) ? fA : fB;
            step_kernel<<<256, 512, 0, stream>>>(inputs, Win, Wrec, bias, hcur, hnxt, out, t);
        }
    }
}